// Round 9
// baseline (1514.188 us; speedup 1.0000x reference)
//
#include <hip/hip_runtime.h>
#include <hip/hip_bf16.h>

#define BN_EPS 1e-4f

typedef __attribute__((ext_vector_type(8))) short short8;   // 8 bf16 = 4 VGPR (MFMA A/B frag)
typedef __attribute__((ext_vector_type(4))) float float4e;  // MFMA C/D frag

__device__ __forceinline__ int rfl(int x) { return __builtin_amdgcn_readfirstlane(x); }

__device__ __forceinline__ float ldf(const __hip_bfloat16* p) { return __bfloat162float(*p); }
__device__ __forceinline__ void stf(__hip_bfloat16* p, float v) { *p = __float2bfloat16(v); }

__device__ __forceinline__ short bfbits(float x) {
    __hip_bfloat16 h = __float2bfloat16(x);
    short s;
    __builtin_memcpy(&s, &h, 2);
    return s;
}
__device__ __forceinline__ short8 cvt8(float4 a, float4 b) {
    short8 r;
    r[0] = bfbits(a.x); r[1] = bfbits(a.y); r[2] = bfbits(a.z); r[3] = bfbits(a.w);
    r[4] = bfbits(b.x); r[5] = bfbits(b.y); r[6] = bfbits(b.z); r[7] = bfbits(b.w);
    return r;
}

// ---- pack W fp32 [27][CIN][COUT] -> bf16 B-fragment table [27][KT][NT][lane][8] ----
// element j of lane = W[t][kt*32 + (lane>>4)*8 + j][nt*16 + (lane&15)]
__global__ __launch_bounds__(256) void k_pack(const float* __restrict__ src,
                                              __hip_bfloat16* __restrict__ dst,
                                              int CIN, int COUT, int KT, int NT, int total) {
    int i = blockIdx.x * 256 + threadIdx.x;
    if (i >= total) return;
    int j = i & 7, lane = (i >> 3) & 63;
    int g = i >> 9;
    int nt = g % NT; g /= NT;
    int kt = g % KT; g /= KT;
    int t = g;
    int q = lane >> 4, c = lane & 15;
    dst[i] = __float2bfloat16(src[((size_t)t * CIN + kt * 32 + q * 8 + j) * COUT + nt * 16 + c]);
}

// ---------------- xv = subconv(feats[N,3], nbr_fine, W_sub) -> bf16 ----------------
__global__ __launch_bounds__(256) void k_xv(const float* __restrict__ feats,
                                            const int* __restrict__ nbr,
                                            const float* __restrict__ W,
                                            __hip_bfloat16* __restrict__ out, int N) {
    int n = blockIdx.x * 256 + threadIdx.x;
    if (n >= N) return;
    float acc[32];
#pragma unroll
    for (int d = 0; d < 32; ++d) acc[d] = 0.f;
    const int* nb = nbr + (size_t)n * 27;
    for (int k = 0; k < 27; ++k) {
        int idx = nb[k];
        if (idx < 0) continue;
        float f0 = feats[(size_t)idx * 3 + 0];
        float f1 = feats[(size_t)idx * 3 + 1];
        float f2 = feats[(size_t)idx * 3 + 2];
        const float* w = W + k * 96;  // k uniform -> scalar loads
#pragma unroll
        for (int d = 0; d < 32; ++d)
            acc[d] += f0 * w[d] + f1 * w[32 + d] + f2 * w[64 + d];
    }
    short8* o = (short8*)(out + (size_t)n * 32);
#pragma unroll
    for (int c = 0; c < 4; ++c) {
        short8 r;
#pragma unroll
        for (int j = 0; j < 8; ++j) r[j] = bfbits(acc[c * 8 + j]);
        o[c] = r;
    }
}

// ---------------- MFMA submanifold conv ----------------
// Wave per 16-row tile. Template knobs (A/B-isolated across rounds 4-8):
//  MAP 0: per-XCD slab, CONTIGUOUS chunk per wave (best for COARSE conv:
//         e1 MODE1 = 368-381 us; interleave regressed it to 466 us — waves
//         contend on lines & lose self-reuse).
//  MAP 1: per-XCD slab, within-slab wave INTERLEAVE (best for FINE convs:
//         instant window ~2 MB fits L2).
//  COMPACT 1: active-tap compaction — wave-OR 27-bit tap mask, order-
//         preserving compact list via ballot-prefix; walk only nact taps
//         (fine grid ~9/27). Bit-identical accumulation order. This round:
//         the compact pipeline is FIVE named slots (4 gathers in flight) —
//         fine convs are gather-LATENCY-bound (MfmaUtil 8%, HBM 6.5%), the
//         old 3-slot/2-in-flight left ~300 cy exposed per tap.
//  COMPACT 0: plain 27-tap loop, 3 slots, per-tap ballots (e1: ~all taps
//         active, and e1 is cache-BW-bound at ~6.6 TB/s — depth won't help).
// Per tap: out[16,COUT] += A(rows)[16,CIN] @ W[tap]. A-frag gathered directly
// from global (lane reads 16B at in + idx*CIN + kt*32 + (lane>>4)*8). Row idx
// from ROW-MAJOR LDS table (stride-27 -> conflict-free, measured 0). All
// pipeline state NAMED scalars (arrays spill to scratch).
// ERRATUM (rounds 1-3, 6): ANY bf16-A instantiation at the e1 shape
// (KT=2, NT=4) — MODE 0 single-src (3 idioms) AND MODE 2 dual-src — runs
// 2.8x slower with ~1.2 GB fetch + ~0.84 GB write per dispatch (scratch
// round-trip signature). dec (KT=2,NT=2,MODE 2) and e0 (KT=1) are clean.
// Pathology is instantiation-shape-bound. e1 is LOCKED to MODE 1 fp32.
// MODE 0: bf16 single src (CIN=32) | 1: fp32 src + in-reg cvt (CIN=64)
// | 2: bf16 dual src A|B halves (CIN=64).
template <int CIN, int COUT, int MODE, int MAP, int COMPACT>
__global__ __launch_bounds__(256, 4) void k_conv(const void* __restrict__ inAv,
                                                 const void* __restrict__ inBv,
                                                 const int* __restrict__ nbr,
                                                 const __hip_bfloat16* __restrict__ Wp,
                                                 __hip_bfloat16* __restrict__ out,
                                                 int nrows,
                                                 float* __restrict__ ssum,
                                                 float* __restrict__ ssq) {
    constexpr int KT = CIN / 32;   // MFMA k-tiles
    constexpr int NT = COUT / 16;  // MFMA n-tiles
    static_assert(KT == 1 || KT == 2, "KT must be 1 or 2");
    __shared__ int sidx[4][432];   // per-wave idx table, row-major [row][tap]
    __shared__ int slist[4][32];   // per-wave compact active-tap list (COMPACT)
    const __hip_bfloat16* inAb = (const __hip_bfloat16*)inAv;
    const __hip_bfloat16* inBb = (const __hip_bfloat16*)inBv;
    const float* inAf = (const float*)inAv;
    const int tid = threadIdx.x;
    const int lane = tid & 63;
    const int wv = tid >> 6;
    const int m15 = lane & 15;
    const int q = lane >> 4;
    int* my = sidx[wv];
    int* lst = slist[wv];
    const int ntile = (nrows + 15) / 16;
    const int b = blockIdx.x;
    // ---- tile range per wave (MAP) ----
    int start, tend, tstep;
    if constexpr (MAP == 0) {
        // bijective XCD swizzle + contiguous chunk per wave
        const int bs = (b & 7) * (gridDim.x >> 3) + (b >> 3);
        const int w = bs * 4 + wv;
        const int nw = gridDim.x * 4;
        const int cq = ntile / nw, cr = ntile % nw;
        start = w * cq + (w < cr ? w : cr);
        tend = start + cq + (w < cr ? 1 : 0);
        tstep = 1;
    } else {
        // per-XCD slab + within-slab wave interleave
        const int xcd = b & 7;
        const int wpx = (gridDim.x >> 3) * 4;
        const int lw = (b >> 3) * 4 + wv;
        const int s0 = (int)(((long long)xcd * ntile) >> 3);
        const int s1 = (int)(((long long)(xcd + 1) * ntile) >> 3);
        start = s0 + lw;
        tend = s1;
        tstep = wpx;
    }
    float sS[NT], sQ[NT];
#pragma unroll
    for (int nt = 0; nt < NT; ++nt) { sS[nt] = 0.f; sQ[nt] = 0.f; }

    const short8 z8 = (short8)(short)0;

    for (int tile = start; tile < tend; tile += tstep) {
        const int row0 = rfl(tile) * 16;
        int nr = nrows - row0;
        nr = nr > 16 ? 16 : nr;
        const int* src = nbr + (size_t)row0 * 27;
        const int tot = nr * 27;
        float4e acc[NT];
#pragma unroll
        for (int nt = 0; nt < NT; ++nt) acc[nt] = (float4e)0.f;

        // named pipeline state (NO arrays -> no dynamic indexing / scratch)
        short8 sA0 = z8, sA1 = z8, sB0 = z8, sB1 = z8, sC0 = z8, sC1 = z8;
        short8 sD0 = z8, sD1 = z8, sE0 = z8, sE1 = z8;
        float4 fA0{}, fA1{}, fA2{}, fA3{};
        float4 fB0{}, fB1{}, fB2{}, fB3{};
        float4 fC0{}, fC1{}, fC2{}, fC3{};

        auto load_g = [&](int ir, short8& s0_, short8& s1_,
                          float4& f0, float4& f1, float4& f2, float4& f3) {
            size_t id = (size_t)(ir < 0 ? 0 : ir);
            if constexpr (MODE == 0) {
                s0_ = *(const short8*)(inAb + id * CIN + q * 8);
                if constexpr (KT == 2)
                    s1_ = *(const short8*)(inAb + id * CIN + 32 + q * 8);
            } else if constexpr (MODE == 2) {
                s0_ = *(const short8*)(inAb + id * 32 + q * 8);
                s1_ = *(const short8*)(inBb + id * 32 + q * 8);
            } else {
                const float* bb = inAf + id * 64 + q * 8;
                f0 = *(const float4*)(bb);
                f1 = *(const float4*)(bb + 4);
                f2 = *(const float4*)(bb + 32);
                f3 = *(const float4*)(bb + 36);
            }
        };

        auto mfma_tap = [&](int ktap, int irv, short8 a0i, short8 a1i,
                            float4 f0, float4 f1, float4 f2, float4 f3) {
            short8 a0, a1;
            if constexpr (MODE == 1) {
                a0 = cvt8(f0, f1);
                a1 = cvt8(f2, f3);
            } else {
                a0 = a0i;
                a1 = a1i;
            }
            a0 = (irv >= 0) ? a0 : z8;
            if constexpr (KT == 2) a1 = (irv >= 0) ? a1 : z8;
            const short8* bp = (const short8*)Wp + (size_t)ktap * (KT * NT * 64) + lane;
#pragma unroll
            for (int nt = 0; nt < NT; ++nt) {
                acc[nt] = __builtin_amdgcn_mfma_f32_16x16x32_bf16(a0, bp[nt * 64], acc[nt], 0, 0, 0);
                if constexpr (KT == 2)
                    acc[nt] = __builtin_amdgcn_mfma_f32_16x16x32_bf16(a1, bp[(NT + nt) * 64], acc[nt], 0, 0, 0);
            }
        };

        if constexpr (COMPACT) {
            // ---- stage idx row-major + tap-activity mask + compact list ----
            unsigned ab = 0;
            for (int t = lane; t < 432; t += 64) {
                int v = (t < tot) ? src[t] : -1;
                my[t] = v;
                if (v >= 0) ab |= (1u << (t % 27));
            }
#pragma unroll
            for (int s = 1; s < 64; s <<= 1) ab |= __shfl_xor((int)ab, s);
            {
                bool act = (lane < 27) && ((ab >> lane) & 1u);
                unsigned long long bal = __ballot(act);
                if (act) lst[__popcll(bal & ((1ull << lane) - 1ull))] = lane;
            }
            const int nact = __popc((int)ab);  // wave-uniform

            // ---- 5-slot pipeline: 4 gathers in flight ----
            int kA = (0 < nact) ? lst[0] : 0;
            int kB = (1 < nact) ? lst[1] : 0;
            int kC = (2 < nact) ? lst[2] : 0;
            int kD = (3 < nact) ? lst[3] : 0;
            int kE = (4 < nact) ? lst[4] : 0;
            int irA = (0 < nact) ? my[m15 * 27 + kA] : -1;
            int irB = (1 < nact) ? my[m15 * 27 + kB] : -1;
            int irC = (2 < nact) ? my[m15 * 27 + kC] : -1;
            int irD = (3 < nact) ? my[m15 * 27 + kD] : -1;
            int irE = (4 < nact) ? my[m15 * 27 + kE] : -1;
            if (0 < nact) load_g(irA, sA0, sA1, fA0, fA1, fA2, fA3);
            if (1 < nact) load_g(irB, sB0, sB1, fB0, fB1, fB2, fB3);
            if (2 < nact) load_g(irC, sC0, sC1, fC0, fC1, fC2, fC3);
            if (3 < nact) load_g(irD, sD0, sD1, fA0, fA1, fA2, fA3);  // f* unused (MODE!=1)
            for (int i = 0; i < nact; ++i) {
                if (i + 4 < nact) load_g(irE, sE0, sE1, fA0, fA1, fA2, fA3);
                int kF = 0, irF = -1;
                if (i + 5 < nact) { kF = lst[i + 5]; irF = my[m15 * 27 + kF]; }
                mfma_tap(kA, irA, sA0, sA1, fA0, fA1, fA2, fA3);
                kA = kB; kB = kC; kC = kD; kD = kE; kE = kF;
                irA = irB; irB = irC; irC = irD; irD = irE; irE = irF;
                sA0 = sB0; sB0 = sC0; sC0 = sD0; sD0 = sE0;
                if constexpr (KT == 2 || MODE == 2) {
                    sA1 = sB1; sB1 = sC1; sC1 = sD1; sD1 = sE1;
                }
            }
        } else {
            // ---- plain 27-tap loop, 3 slots, per-tap ballots (e1-proven) ----
            for (int t = lane; t < 432; t += 64) my[t] = (t < tot) ? src[t] : -1;
            int irA = my[m15 * 27 + 0];
            int irB = my[m15 * 27 + 1];
            int irC = my[m15 * 27 + 2];
            int mA = rfl((int)(__ballot(irA >= 0) & 0xffff));
            int mB = rfl((int)(__ballot(irB >= 0) & 0xffff));
            if (mA) load_g(irA, sA0, sA1, fA0, fA1, fA2, fA3);
            if (mB) load_g(irB, sB0, sB1, fB0, fB1, fB2, fB3);
            for (int k = 0; k < 27; ++k) {
                int mC = rfl((int)(__ballot(irC >= 0) & 0xffff));
                int irD2 = -1;
                if (k + 3 < 27) irD2 = my[m15 * 27 + (k + 3)];
                if (mC) load_g(irC, sC0, sC1, fC0, fC1, fC2, fC3);
                if (mA) mfma_tap(k, irA, sA0, sA1, fA0, fA1, fA2, fA3);
                mA = mB; mB = mC;
                irA = irB; irB = irC; irC = irD2;
                if constexpr (MODE == 1) {
                    fA0 = fB0; fA1 = fB1; fA2 = fB2; fA3 = fB3;
                    fB0 = fC0; fB1 = fC1; fB2 = fC2; fB3 = fC3;
                } else {
                    sA0 = sB0; sB0 = sC0;
                    if constexpr (KT == 2 || MODE == 2) { sA1 = sB1; sB1 = sC1; }
                }
            }
        }
        // ---- store C (col=lane&15, row=quad*4+reg) + BN stats ----
#pragma unroll
        for (int nt = 0; nt < NT; ++nt) {
#pragma unroll
            for (int r = 0; r < 4; ++r) {
                int rowg = row0 + q * 4 + r;
                if (rowg < nrows) {
                    float v = acc[nt][r];
                    stf(out + (size_t)rowg * COUT + nt * 16 + m15, v);
                    sS[nt] += v;
                    sQ[nt] += v * v;
                }
            }
        }
    }
    // ---- stats: reduce over quads (same col), one atomic per (col,nt) ----
#pragma unroll
    for (int nt = 0; nt < NT; ++nt) {
        float v = sS[nt], w2 = sQ[nt];
        v += __shfl_xor(v, 16); v += __shfl_xor(v, 32);
        w2 += __shfl_xor(w2, 16); w2 += __shfl_xor(w2, 32);
        if (lane < 16) {
            atomicAdd(&ssum[nt * 16 + lane], v);
            atomicAdd(&ssq[nt * 16 + lane], w2);
        }
    }
}

// ---------------- BN finalize: scale/shift from sums ----------------
__global__ void k_fin(const float* __restrict__ ssum, const float* __restrict__ ssq,
                      const float* __restrict__ g, const float* __restrict__ b,
                      float* __restrict__ scale, float* __restrict__ shift,
                      int C, float invN) {
    int c = blockIdx.x * blockDim.x + threadIdx.x;
    if (c >= C) return;
    float mu = ssum[c] * invN;
    float var = fmaxf(ssq[c] * invN - mu * mu, 0.f);
    float s = g[c] * rsqrtf(var + BN_EPS);
    scale[c] = s;
    shift[c] = b[c] - mu * s;
}

// ---- e0 = bnrelu(e0raw) in place (bf16); down[parent] += e0 @ W_down[off] (fp32 atomics) ----
__global__ __launch_bounds__(256) void k_down(__hip_bfloat16* __restrict__ e0,
                                              const int* __restrict__ parent,
                                              const int* __restrict__ child,
                                              const float* __restrict__ Wd,
                                              const float* __restrict__ sc,
                                              const float* __restrict__ sh,
                                              float* __restrict__ down, int N) {
    const int lane = threadIdx.x & 63;
    int wid = blockIdx.x * 4 + (threadIdx.x >> 6);
    int nw = gridDim.x * 4;
    for (int row = wid; row < N; row += nw) {
        int urow = rfl(row);
        float v = 0.f;
        if (lane < 32) {
            float r = ldf(e0 + (size_t)urow * 32 + lane);
            v = fmaxf(fmaf(r, sc[lane], sh[lane]), 0.f);
            stf(e0 + (size_t)urow * 32 + lane, v);  // post-BN e0, consumed by dec
        }
        int par = rfl(parent[urow]);
        int off = rfl(child[urow]);
        float acc = 0.f;
        const float* wb = Wd + (size_t)off * 2048 + lane;  // W_down[off][c][lane]
#pragma unroll
        for (int c = 0; c < 32; ++c)
            acc = fmaf(__shfl(v, c), wb[c * 64], acc);
        atomicAdd(&down[(size_t)par * 64 + lane], acc);
    }
}

// ---- up[n] = bnrelu(e1raw)[parent[n]] @ W_up[off[n]] -> bf16 ----
__global__ __launch_bounds__(256) void k_up(const __hip_bfloat16* __restrict__ e1raw,
                                            const int* __restrict__ parent,
                                            const int* __restrict__ child,
                                            const float* __restrict__ Wu,
                                            const float* __restrict__ sc,
                                            const float* __restrict__ sh,
                                            __hip_bfloat16* __restrict__ up, int N) {
    const int lane = threadIdx.x & 63;
    int wid = blockIdx.x * 4 + (threadIdx.x >> 6);
    int nw = gridDim.x * 4;
    for (int row = wid; row < N; row += nw) {
        int urow = rfl(row);
        int par = rfl(parent[urow]);
        int off = rfl(child[urow]);
        float e = ldf(e1raw + (size_t)par * 64 + lane);
        float v = fmaxf(fmaf(e, sc[lane], sh[lane]), 0.f);  // BN on the fly
        int d = lane & 31, hi = lane >> 5;
        float acc = 0.f;
        const float* wb = Wu + (size_t)off * 2048 + (size_t)hi * 1024 + d;
#pragma unroll
        for (int c = 0; c < 32; ++c)
            acc = fmaf(__shfl(v, hi * 32 + c), wb[c * 32], acc);
        acc += __shfl_xor(acc, 32);
        if (hi == 0) stf(up + (size_t)urow * 32 + d, acc);
    }
}

// ---- feature = bnrelu(decraw); y = feature @ W_lin + b_lin ----
__global__ __launch_bounds__(256) void k_out(const __hip_bfloat16* __restrict__ dec,
                                             const float* __restrict__ sc,
                                             const float* __restrict__ sh,
                                             const float* __restrict__ Wl,
                                             const float* __restrict__ bl,
                                             float* __restrict__ y,
                                             float* __restrict__ feat, int N) {
    int n = blockIdx.x * 256 + threadIdx.x;
    if (n >= N) return;
    float f[32];
    const __hip_bfloat162* p = (const __hip_bfloat162*)(dec + (size_t)n * 32);
#pragma unroll
    for (int j = 0; j < 16; ++j) {
        float2 t = __bfloat1622float2(p[j]);
        f[2 * j + 0] = fmaxf(fmaf(t.x, sc[2 * j + 0], sh[2 * j + 0]), 0.f);
        f[2 * j + 1] = fmaxf(fmaf(t.y, sc[2 * j + 1], sh[2 * j + 1]), 0.f);
    }
    float4* fo = (float4*)(feat + (size_t)n * 32);
#pragma unroll
    for (int j = 0; j < 8; ++j)
        fo[j] = make_float4(f[4 * j], f[4 * j + 1], f[4 * j + 2], f[4 * j + 3]);
    float acc[20];
#pragma unroll
    for (int qq = 0; qq < 20; ++qq) acc[qq] = bl[qq];
#pragma unroll
    for (int c = 0; c < 32; ++c) {
        float fc = f[c];
#pragma unroll
        for (int qq = 0; qq < 20; ++qq) acc[qq] = fmaf(fc, Wl[c * 20 + qq], acc[qq]);
    }
    float4* yo = (float4*)(y + (size_t)n * 20);
#pragma unroll
    for (int j = 0; j < 5; ++j)
        yo[j] = make_float4(acc[4 * j], acc[4 * j + 1], acc[4 * j + 2], acc[4 * j + 3]);
}

extern "C" void kernel_launch(void* const* d_in, const int* in_sizes, int n_in,
                              void* d_out, int out_size, void* d_ws, size_t ws_size,
                              hipStream_t stream) {
    const float* feats = (const float*)d_in[0];
    const int* nbr_f   = (const int*)d_in[1];
    const int* nbr_c   = (const int*)d_in[2];
    const int* parent  = (const int*)d_in[3];
    const int* child   = (const int*)d_in[4];
    const float* W_sub = (const float*)d_in[5];
    const float* W_e0  = (const float*)d_in[6];
    const float* g0    = (const float*)d_in[7];
    const float* b0    = (const float*)d_in[8];
    const float* W_dn  = (const float*)d_in[9];
    const float* W_e1  = (const float*)d_in[10];
    const float* g1    = (const float*)d_in[11];
    const float* b1    = (const float*)d_in[12];
    const float* W_up  = (const float*)d_in[13];
    const float* W_dec = (const float*)d_in[14];
    const float* g_o   = (const float*)d_in[15];
    const float* b_o   = (const float*)d_in[16];
    const float* W_lin = (const float*)d_in[17];
    const float* b_lin = (const float*)d_in[18];

    const int N = in_sizes[0] / 3;
    const int M = in_sizes[2] / 27;

    // --- workspace: xvb bf16 [0..N*16 fl) (steps 3-4) / down fp32 [0..M*64 fl)
    // (steps 5-8) / up bf16 [0..N*16 fl) + decraw bf16 [N*16..N*32 fl)
    // (steps 10-13); stats at R ---
    float* wsf = (float*)d_ws;
    size_t R = (size_t)M * 64;
    if ((size_t)N * 32 > R) R = (size_t)N * 32;
    __hip_bfloat16* xvb = (__hip_bfloat16*)wsf;
    float* down = wsf;
    __hip_bfloat16* up     = (__hip_bfloat16*)wsf;
    __hip_bfloat16* decraw = (__hip_bfloat16*)(wsf + (size_t)N * 16);
    float* stats = wsf + R;
    // stats map: 0 sum0[32] | 32 sq0[32] | 64 sum1[64] | 128 sq1[64] |
    //            192 sumo[32] | 224 sqo[32] | 256 scale0 | 288 shift0 |
    //            320 scale1[64] | 384 shift1[64] | 448 scaleo | 480 shifto

    // --- d_out scratch: e0 bf16 [0..N*16 fl), e1raw bf16 [N*16..N*16+M*32 fl),
    // packed weights after; all dead before k_out writes y/feat ---
    __hip_bfloat16* e0    = (__hip_bfloat16*)d_out;
    __hip_bfloat16* e1raw = (__hip_bfloat16*)((float*)d_out + (size_t)N * 16);
    __hip_bfloat16* Wp0   = (__hip_bfloat16*)((float*)d_out + (size_t)N * 16 + (size_t)M * 32);
    const int T0 = 27 * 1 * 2 * 512;  // e0 pack: KT1 NT2
    const int T1 = 27 * 2 * 4 * 512;  // e1 pack: KT2 NT4
    const int T2 = 27 * 2 * 2 * 512;  // dec pack: KT2 NT2
    __hip_bfloat16* Wp1 = Wp0 + T0;
    __hip_bfloat16* Wp2 = Wp1 + T1;
    float* y    = (float*)d_out;
    float* feat = y + (size_t)N * 20;

    const int nblk = (N + 255) / 256;
    const int G = 2048;  // multiple of 8 (per-XCD slab / swizzle)

    hipMemsetAsync(stats, 0, 256 * sizeof(float), stream);
    k_pack<<<(T0 + 255) / 256, 256, 0, stream>>>(W_e0, Wp0, 32, 32, 1, 2, T0);
    k_pack<<<(T1 + 255) / 256, 256, 0, stream>>>(W_e1, Wp1, 64, 64, 2, 4, T1);
    k_pack<<<(T2 + 255) / 256, 256, 0, stream>>>(W_dec, Wp2, 64, 32, 2, 2, T2);

    k_xv<<<nblk, 256, 0, stream>>>(feats, nbr_f, W_sub, xvb, N);
    // fine convs: interleave + compaction + 5-slot pipeline
    k_conv<32, 32, 0, 1, 1><<<G, 256, 0, stream>>>(xvb, nullptr, nbr_f, Wp0, e0, N,
                                                   stats + 0, stats + 32);
    // xvb dead; zero `down` (same region) for the atomic segment-sum
    hipMemsetAsync(down, 0, (size_t)M * 64 * sizeof(float), stream);
    k_fin<<<1, 64, 0, stream>>>(stats + 0, stats + 32, g0, b0,
                                stats + 256, stats + 288, 32, 1.f / (float)N);
    k_down<<<G, 256, 0, stream>>>(e0, parent, child, W_dn,
                                  stats + 256, stats + 288, down, N);
    // e1: MODE 1 fp32, contiguous-chunk map, NO compaction (proven 368us)
    k_conv<64, 64, 1, 0, 0><<<G, 256, 0, stream>>>(down, nullptr, nbr_c, Wp1, e1raw, M,
                                                   stats + 64, stats + 128);
    k_fin<<<1, 64, 0, stream>>>(stats + 64, stats + 128, g1, b1,
                                stats + 320, stats + 384, 64, 1.f / (float)M);
    k_up<<<G, 256, 0, stream>>>(e1raw, parent, child, W_up,
                                stats + 320, stats + 384, up, N);
    k_conv<64, 32, 2, 1, 1><<<G, 256, 0, stream>>>(e0, up, nbr_f, Wp2, decraw, N,
                                                   stats + 192, stats + 224);
    k_fin<<<1, 64, 0, stream>>>(stats + 192, stats + 224, g_o, b_o,
                                stats + 448, stats + 480, 32, 1.f / (float)N);
    k_out<<<nblk, 256, 0, stream>>>(decraw, stats + 448, stats + 480, W_lin, b_lin,
                                    y, feat, N);
}

// Round 10
// 1498.112 us; speedup vs baseline: 1.0107x; 1.0107x over previous
//
#include <hip/hip_runtime.h>
#include <hip/hip_bf16.h>

#define BN_EPS 1e-4f

typedef __attribute__((ext_vector_type(8))) short short8;   // 8 bf16 = 4 VGPR (MFMA A/B frag)
typedef __attribute__((ext_vector_type(4))) float float4e;  // MFMA C/D frag

__device__ __forceinline__ int rfl(int x) { return __builtin_amdgcn_readfirstlane(x); }

__device__ __forceinline__ float ldf(const __hip_bfloat16* p) { return __bfloat162float(*p); }
__device__ __forceinline__ void stf(__hip_bfloat16* p, float v) { *p = __float2bfloat16(v); }

__device__ __forceinline__ short bfbits(float x) {
    __hip_bfloat16 h = __float2bfloat16(x);
    short s;
    __builtin_memcpy(&s, &h, 2);
    return s;
}
__device__ __forceinline__ short8 cvt8(float4 a, float4 b) {
    short8 r;
    r[0] = bfbits(a.x); r[1] = bfbits(a.y); r[2] = bfbits(a.z); r[3] = bfbits(a.w);
    r[4] = bfbits(b.x); r[5] = bfbits(b.y); r[6] = bfbits(b.z); r[7] = bfbits(b.w);
    return r;
}

// ---- pack W fp32 [27][CIN][COUT] -> bf16 B-fragment table [27][KT][NT][lane][8] ----
// element j of lane = W[t][kt*32 + (lane>>4)*8 + j][nt*16 + (lane&15)]
__global__ __launch_bounds__(256) void k_pack(const float* __restrict__ src,
                                              __hip_bfloat16* __restrict__ dst,
                                              int CIN, int COUT, int KT, int NT, int total) {
    int i = blockIdx.x * 256 + threadIdx.x;
    if (i >= total) return;
    int j = i & 7, lane = (i >> 3) & 63;
    int g = i >> 9;
    int nt = g % NT; g /= NT;
    int kt = g % KT; g /= KT;
    int t = g;
    int q = lane >> 4, c = lane & 15;
    dst[i] = __float2bfloat16(src[((size_t)t * CIN + kt * 32 + q * 8 + j) * COUT + nt * 16 + c]);
}

// ---------------- xv = subconv(feats[N,3], nbr_fine, W_sub) -> bf16 ----------------
__global__ __launch_bounds__(256) void k_xv(const float* __restrict__ feats,
                                            const int* __restrict__ nbr,
                                            const float* __restrict__ W,
                                            __hip_bfloat16* __restrict__ out, int N) {
    int n = blockIdx.x * 256 + threadIdx.x;
    if (n >= N) return;
    float acc[32];
#pragma unroll
    for (int d = 0; d < 32; ++d) acc[d] = 0.f;
    const int* nb = nbr + (size_t)n * 27;
    for (int k = 0; k < 27; ++k) {
        int idx = nb[k];
        if (idx < 0) continue;
        float f0 = feats[(size_t)idx * 3 + 0];
        float f1 = feats[(size_t)idx * 3 + 1];
        float f2 = feats[(size_t)idx * 3 + 2];
        const float* w = W + k * 96;  // k uniform -> scalar loads
#pragma unroll
        for (int d = 0; d < 32; ++d)
            acc[d] += f0 * w[d] + f1 * w[32 + d] + f2 * w[64 + d];
    }
    short8* o = (short8*)(out + (size_t)n * 32);
#pragma unroll
    for (int c = 0; c < 4; ++c) {
        short8 r;
#pragma unroll
        for (int j = 0; j < 8; ++j) r[j] = bfbits(acc[c * 8 + j]);
        o[c] = r;
    }
}

// ---------------- MFMA submanifold conv ----------------
// Wave per 16-row tile. Template knobs (A/B-isolated across rounds 4-9):
//  MAP 0: per-XCD slab, CONTIGUOUS chunk per wave (best for COARSE conv:
//         e1 MODE1 = 368-381 us; interleave regressed it to 466 us).
//  MAP 1: per-XCD slab, within-slab wave INTERLEAVE (best for FINE convs:
//         instant window ~2 MB fits L2).
//  COMPACT 1: active-tap compaction (wave-OR 27-bit mask, order-preserving
//         list via ballot-prefix; walk only nact taps — fine grid ~9/27).
//         Pipeline is a ROTATED 3-slot modulo schedule: iteration i consumes
//         fixed slot (i%3) and reloads THAT slot with tap i+3 — NO register
//         shifts. Round-9 lesson: shift-based pipelines (sA=sB;sB=sC) make
//         the shift's v_mov depend on the NEWEST load -> compiler emits
//         s_waitcnt vmcnt(0) every iteration -> effective depth 1 regardless
//         of slot count (5-slot was null). Rotation keeps 2 loads in flight.
//  COMPACT 0: plain 27-tap loop, 3 shifting slots, per-tap ballots — e1 only
//         (~all taps active; e1 is cache-BW-bound at ~6.6 TB/s effective, so
//         pipeline depth is irrelevant there). Kept byte-identical to the
//         1490us-proven round-8 build to avoid codegen perturbation.
// Per tap: out[16,COUT] += A(rows)[16,CIN] @ W[tap]. A-frag gathered directly
// from global (lane reads 16B at in + idx*CIN + kt*32 + (lane>>4)*8). Row idx
// from ROW-MAJOR LDS table (stride-27 -> conflict-free, measured 0). All
// pipeline state NAMED scalars (arrays spill to scratch).
// ERRATUM (rounds 1-3, 6): ANY bf16-A instantiation at the e1 shape
// (KT=2, NT=4) — MODE 0 single-src (3 idioms) AND MODE 2 dual-src — runs
// 2.8x slower with ~1.2 GB fetch + ~0.84 GB write per dispatch (scratch
// round-trip signature). dec (KT=2,NT=2,MODE 2) and e0 (KT=1) are clean.
// Pathology is instantiation-shape-bound. e1 is LOCKED to MODE 1 fp32.
// MODE 0: bf16 single src (CIN=32) | 1: fp32 src + in-reg cvt (CIN=64)
// | 2: bf16 dual src A|B halves (CIN=64).
template <int CIN, int COUT, int MODE, int MAP, int COMPACT>
__global__ __launch_bounds__(256, 4) void k_conv(const void* __restrict__ inAv,
                                                 const void* __restrict__ inBv,
                                                 const int* __restrict__ nbr,
                                                 const __hip_bfloat16* __restrict__ Wp,
                                                 __hip_bfloat16* __restrict__ out,
                                                 int nrows,
                                                 float* __restrict__ ssum,
                                                 float* __restrict__ ssq) {
    constexpr int KT = CIN / 32;   // MFMA k-tiles
    constexpr int NT = COUT / 16;  // MFMA n-tiles
    static_assert(KT == 1 || KT == 2, "KT must be 1 or 2");
    static_assert(!(COMPACT == 1 && MODE == 1), "compact path is bf16-only");
    __shared__ int sidx[4][432];   // per-wave idx table, row-major [row][tap]
    __shared__ int slist[4][32];   // per-wave compact active-tap list (COMPACT)
    const __hip_bfloat16* inAb = (const __hip_bfloat16*)inAv;
    const __hip_bfloat16* inBb = (const __hip_bfloat16*)inBv;
    const float* inAf = (const float*)inAv;
    const int tid = threadIdx.x;
    const int lane = tid & 63;
    const int wv = tid >> 6;
    const int m15 = lane & 15;
    const int q = lane >> 4;
    int* my = sidx[wv];
    int* lst = slist[wv];
    const int ntile = (nrows + 15) / 16;
    const int b = blockIdx.x;
    // ---- tile range per wave (MAP) ----
    int start, tend, tstep;
    if constexpr (MAP == 0) {
        // bijective XCD swizzle + contiguous chunk per wave
        const int bs = (b & 7) * (gridDim.x >> 3) + (b >> 3);
        const int w = bs * 4 + wv;
        const int nw = gridDim.x * 4;
        const int cq = ntile / nw, cr = ntile % nw;
        start = w * cq + (w < cr ? w : cr);
        tend = start + cq + (w < cr ? 1 : 0);
        tstep = 1;
    } else {
        // per-XCD slab + within-slab wave interleave
        const int xcd = b & 7;
        const int wpx = (gridDim.x >> 3) * 4;
        const int lw = (b >> 3) * 4 + wv;
        const int s0 = (int)(((long long)xcd * ntile) >> 3);
        const int s1 = (int)(((long long)(xcd + 1) * ntile) >> 3);
        start = s0 + lw;
        tend = s1;
        tstep = wpx;
    }
    float sS[NT], sQ[NT];
#pragma unroll
    for (int nt = 0; nt < NT; ++nt) { sS[nt] = 0.f; sQ[nt] = 0.f; }

    const short8 z8 = (short8)(short)0;

    for (int tile = start; tile < tend; tile += tstep) {
        const int row0 = rfl(tile) * 16;
        int nr = nrows - row0;
        nr = nr > 16 ? 16 : nr;
        const int* src = nbr + (size_t)row0 * 27;
        const int tot = nr * 27;
        float4e acc[NT];
#pragma unroll
        for (int nt = 0; nt < NT; ++nt) acc[nt] = (float4e)0.f;

        if constexpr (COMPACT) {
            // ---- stage idx row-major + tap-activity mask + compact list ----
            unsigned ab = 0;
            for (int t = lane; t < 432; t += 64) {
                int v = (t < tot) ? src[t] : -1;
                my[t] = v;
                if (v >= 0) ab |= (1u << (t % 27));
            }
#pragma unroll
            for (int s = 1; s < 64; s <<= 1) ab |= __shfl_xor((int)ab, s);
            {
                bool act = (lane < 27) && ((ab >> lane) & 1u);
                unsigned long long bal = __ballot(act);
                if (act) lst[__popcll(bal & ((1ull << lane) - 1ull))] = lane;
            }
            const int nact = __popc((int)ab);  // wave-uniform

            auto load_s = [&](int ir, short8& s0_, short8& s1_) {
                size_t id = (size_t)(ir < 0 ? 0 : ir);
                if constexpr (MODE == 0) {
                    s0_ = *(const short8*)(inAb + id * CIN + q * 8);
                    if constexpr (KT == 2)
                        s1_ = *(const short8*)(inAb + id * CIN + 32 + q * 8);
                } else {  // MODE 2
                    s0_ = *(const short8*)(inAb + id * 32 + q * 8);
                    s1_ = *(const short8*)(inBb + id * 32 + q * 8);
                }
            };
            auto mfma_s = [&](int ktap, int irv, short8 a0, short8 a1) {
                a0 = (irv >= 0) ? a0 : z8;
                if constexpr (KT == 2) a1 = (irv >= 0) ? a1 : z8;
                const short8* bp = (const short8*)Wp + (size_t)ktap * (KT * NT * 64) + lane;
#pragma unroll
                for (int nt = 0; nt < NT; ++nt) {
                    acc[nt] = __builtin_amdgcn_mfma_f32_16x16x32_bf16(a0, bp[nt * 64], acc[nt], 0, 0, 0);
                    if constexpr (KT == 2)
                        acc[nt] = __builtin_amdgcn_mfma_f32_16x16x32_bf16(a1, bp[(NT + nt) * 64], acc[nt], 0, 0, 0);
                }
            };

            // ---- rotated 3-slot modulo pipeline (no register shifts) ----
            short8 sX0 = z8, sX1 = z8, sY0 = z8, sY1 = z8, sZ0 = z8, sZ1 = z8;
            int kX = 0, kY = 0, kZ = 0, irX = -1, irY = -1, irZ = -1;
            if (0 < nact) { kX = lst[0]; irX = my[m15 * 27 + kX]; load_s(irX, sX0, sX1); }
            if (1 < nact) { kY = lst[1]; irY = my[m15 * 27 + kY]; load_s(irY, sY0, sY1); }
            if (2 < nact) { kZ = lst[2]; irZ = my[m15 * 27 + kZ]; load_s(irZ, sZ0, sZ1); }
            int i = 0;
            while (i < nact) {
                mfma_s(kX, irX, sX0, sX1);
                if (i + 3 < nact) { kX = lst[i + 3]; irX = my[m15 * 27 + kX]; load_s(irX, sX0, sX1); }
                if (++i >= nact) break;
                mfma_s(kY, irY, sY0, sY1);
                if (i + 3 < nact) { kY = lst[i + 3]; irY = my[m15 * 27 + kY]; load_s(irY, sY0, sY1); }
                if (++i >= nact) break;
                mfma_s(kZ, irZ, sZ0, sZ1);
                if (i + 3 < nact) { kZ = lst[i + 3]; irZ = my[m15 * 27 + kZ]; load_s(irZ, sZ0, sZ1); }
                ++i;
            }
        } else {
            // ---- plain 27-tap loop, 3 shifting slots, per-tap ballots ----
            // (byte-identical to the 1490us round-8 build; e1 only)
            for (int t = lane; t < 432; t += 64) my[t] = (t < tot) ? src[t] : -1;

            short8 sA0 = z8, sA1 = z8, sB0 = z8, sB1 = z8, sC0 = z8, sC1 = z8;
            float4 fA0{}, fA1{}, fA2{}, fA3{};
            float4 fB0{}, fB1{}, fB2{}, fB3{};
            float4 fC0{}, fC1{}, fC2{}, fC3{};

            auto load_g = [&](int ir, short8& s0_, short8& s1_,
                              float4& f0, float4& f1, float4& f2, float4& f3) {
                size_t id = (size_t)(ir < 0 ? 0 : ir);
                if constexpr (MODE == 0) {
                    s0_ = *(const short8*)(inAb + id * CIN + q * 8);
                    if constexpr (KT == 2)
                        s1_ = *(const short8*)(inAb + id * CIN + 32 + q * 8);
                } else if constexpr (MODE == 2) {
                    s0_ = *(const short8*)(inAb + id * 32 + q * 8);
                    s1_ = *(const short8*)(inBb + id * 32 + q * 8);
                } else {
                    const float* bb = inAf + id * 64 + q * 8;
                    f0 = *(const float4*)(bb);
                    f1 = *(const float4*)(bb + 4);
                    f2 = *(const float4*)(bb + 32);
                    f3 = *(const float4*)(bb + 36);
                }
            };

            int irA = my[m15 * 27 + 0];
            int irB = my[m15 * 27 + 1];
            int irC = my[m15 * 27 + 2];
            int mA = rfl((int)(__ballot(irA >= 0) & 0xffff));
            int mB = rfl((int)(__ballot(irB >= 0) & 0xffff));
            if (mA) load_g(irA, sA0, sA1, fA0, fA1, fA2, fA3);
            if (mB) load_g(irB, sB0, sB1, fB0, fB1, fB2, fB3);
            for (int k = 0; k < 27; ++k) {
                int mC = rfl((int)(__ballot(irC >= 0) & 0xffff));
                int irD = -1;
                if (k + 3 < 27) irD = my[m15 * 27 + (k + 3)];
                if (mC) load_g(irC, sC0, sC1, fC0, fC1, fC2, fC3);
                if (mA) {
                    short8 a0, a1;
                    if constexpr (MODE == 1) {
                        a0 = cvt8(fA0, fA1);
                        a1 = cvt8(fA2, fA3);
                    } else {
                        a0 = sA0;
                        a1 = sA1;
                    }
                    a0 = (irA >= 0) ? a0 : z8;
                    if constexpr (KT == 2) a1 = (irA >= 0) ? a1 : z8;
                    const short8* bp = (const short8*)Wp + (size_t)k * KT * NT * 64 + lane;
#pragma unroll
                    for (int nt = 0; nt < NT; ++nt) {
                        acc[nt] = __builtin_amdgcn_mfma_f32_16x16x32_bf16(a0, bp[nt * 64], acc[nt], 0, 0, 0);
                        if constexpr (KT == 2)
                            acc[nt] = __builtin_amdgcn_mfma_f32_16x16x32_bf16(a1, bp[(NT + nt) * 64], acc[nt], 0, 0, 0);
                    }
                }
                mA = mB; mB = mC;
                irA = irB; irB = irC; irC = irD;
                if constexpr (MODE == 1) {
                    fA0 = fB0; fA1 = fB1; fA2 = fB2; fA3 = fB3;
                    fB0 = fC0; fB1 = fC1; fB2 = fC2; fB3 = fC3;
                } else {
                    sA0 = sB0; sB0 = sC0;
                    if constexpr (KT == 2) { sA1 = sB1; sB1 = sC1; }
                }
            }
        }
        // ---- store C (col=lane&15, row=quad*4+reg) + BN stats ----
#pragma unroll
        for (int nt = 0; nt < NT; ++nt) {
#pragma unroll
            for (int r = 0; r < 4; ++r) {
                int rowg = row0 + q * 4 + r;
                if (rowg < nrows) {
                    float v = acc[nt][r];
                    stf(out + (size_t)rowg * COUT + nt * 16 + m15, v);
                    sS[nt] += v;
                    sQ[nt] += v * v;
                }
            }
        }
    }
    // ---- stats: reduce over quads (same col), one atomic per (col,nt) ----
#pragma unroll
    for (int nt = 0; nt < NT; ++nt) {
        float v = sS[nt], w2 = sQ[nt];
        v += __shfl_xor(v, 16); v += __shfl_xor(v, 32);
        w2 += __shfl_xor(w2, 16); w2 += __shfl_xor(w2, 32);
        if (lane < 16) {
            atomicAdd(&ssum[nt * 16 + lane], v);
            atomicAdd(&ssq[nt * 16 + lane], w2);
        }
    }
}

// ---------------- BN finalize: scale/shift from sums ----------------
__global__ void k_fin(const float* __restrict__ ssum, const float* __restrict__ ssq,
                      const float* __restrict__ g, const float* __restrict__ b,
                      float* __restrict__ scale, float* __restrict__ shift,
                      int C, float invN) {
    int c = blockIdx.x * blockDim.x + threadIdx.x;
    if (c >= C) return;
    float mu = ssum[c] * invN;
    float var = fmaxf(ssq[c] * invN - mu * mu, 0.f);
    float s = g[c] * rsqrtf(var + BN_EPS);
    scale[c] = s;
    shift[c] = b[c] - mu * s;
}

// ---- e0 = bnrelu(e0raw) in place (bf16); down[parent] += e0 @ W_down[off] (fp32 atomics) ----
__global__ __launch_bounds__(256) void k_down(__hip_bfloat16* __restrict__ e0,
                                              const int* __restrict__ parent,
                                              const int* __restrict__ child,
                                              const float* __restrict__ Wd,
                                              const float* __restrict__ sc,
                                              const float* __restrict__ sh,
                                              float* __restrict__ down, int N) {
    const int lane = threadIdx.x & 63;
    int wid = blockIdx.x * 4 + (threadIdx.x >> 6);
    int nw = gridDim.x * 4;
    for (int row = wid; row < N; row += nw) {
        int urow = rfl(row);
        float v = 0.f;
        if (lane < 32) {
            float r = ldf(e0 + (size_t)urow * 32 + lane);
            v = fmaxf(fmaf(r, sc[lane], sh[lane]), 0.f);
            stf(e0 + (size_t)urow * 32 + lane, v);  // post-BN e0, consumed by dec
        }
        int par = rfl(parent[urow]);
        int off = rfl(child[urow]);
        float acc = 0.f;
        const float* wb = Wd + (size_t)off * 2048 + lane;  // W_down[off][c][lane]
#pragma unroll
        for (int c = 0; c < 32; ++c)
            acc = fmaf(__shfl(v, c), wb[c * 64], acc);
        atomicAdd(&down[(size_t)par * 64 + lane], acc);
    }
}

// ---- up[n] = bnrelu(e1raw)[parent[n]] @ W_up[off[n]] -> bf16 ----
__global__ __launch_bounds__(256) void k_up(const __hip_bfloat16* __restrict__ e1raw,
                                            const int* __restrict__ parent,
                                            const int* __restrict__ child,
                                            const float* __restrict__ Wu,
                                            const float* __restrict__ sc,
                                            const float* __restrict__ sh,
                                            __hip_bfloat16* __restrict__ up, int N) {
    const int lane = threadIdx.x & 63;
    int wid = blockIdx.x * 4 + (threadIdx.x >> 6);
    int nw = gridDim.x * 4;
    for (int row = wid; row < N; row += nw) {
        int urow = rfl(row);
        int par = rfl(parent[urow]);
        int off = rfl(child[urow]);
        float e = ldf(e1raw + (size_t)par * 64 + lane);
        float v = fmaxf(fmaf(e, sc[lane], sh[lane]), 0.f);  // BN on the fly
        int d = lane & 31, hi = lane >> 5;
        float acc = 0.f;
        const float* wb = Wu + (size_t)off * 2048 + (size_t)hi * 1024 + d;
#pragma unroll
        for (int c = 0; c < 32; ++c)
            acc = fmaf(__shfl(v, hi * 32 + c), wb[c * 32], acc);
        acc += __shfl_xor(acc, 32);
        if (hi == 0) stf(up + (size_t)urow * 32 + d, acc);
    }
}

// ---- feature = bnrelu(decraw); y = feature @ W_lin + b_lin ----
__global__ __launch_bounds__(256) void k_out(const __hip_bfloat16* __restrict__ dec,
                                             const float* __restrict__ sc,
                                             const float* __restrict__ sh,
                                             const float* __restrict__ Wl,
                                             const float* __restrict__ bl,
                                             float* __restrict__ y,
                                             float* __restrict__ feat, int N) {
    int n = blockIdx.x * 256 + threadIdx.x;
    if (n >= N) return;
    float f[32];
    const __hip_bfloat162* p = (const __hip_bfloat162*)(dec + (size_t)n * 32);
#pragma unroll
    for (int j = 0; j < 16; ++j) {
        float2 t = __bfloat1622float2(p[j]);
        f[2 * j + 0] = fmaxf(fmaf(t.x, sc[2 * j + 0], sh[2 * j + 0]), 0.f);
        f[2 * j + 1] = fmaxf(fmaf(t.y, sc[2 * j + 1], sh[2 * j + 1]), 0.f);
    }
    float4* fo = (float4*)(feat + (size_t)n * 32);
#pragma unroll
    for (int j = 0; j < 8; ++j)
        fo[j] = make_float4(f[4 * j], f[4 * j + 1], f[4 * j + 2], f[4 * j + 3]);
    float acc[20];
#pragma unroll
    for (int qq = 0; qq < 20; ++qq) acc[qq] = bl[qq];
#pragma unroll
    for (int c = 0; c < 32; ++c) {
        float fc = f[c];
#pragma unroll
        for (int qq = 0; qq < 20; ++qq) acc[qq] = fmaf(fc, Wl[c * 20 + qq], acc[qq]);
    }
    float4* yo = (float4*)(y + (size_t)n * 20);
#pragma unroll
    for (int j = 0; j < 5; ++j)
        yo[j] = make_float4(acc[4 * j], acc[4 * j + 1], acc[4 * j + 2], acc[4 * j + 3]);
}

extern "C" void kernel_launch(void* const* d_in, const int* in_sizes, int n_in,
                              void* d_out, int out_size, void* d_ws, size_t ws_size,
                              hipStream_t stream) {
    const float* feats = (const float*)d_in[0];
    const int* nbr_f   = (const int*)d_in[1];
    const int* nbr_c   = (const int*)d_in[2];
    const int* parent  = (const int*)d_in[3];
    const int* child   = (const int*)d_in[4];
    const float* W_sub = (const float*)d_in[5];
    const float* W_e0  = (const float*)d_in[6];
    const float* g0    = (const float*)d_in[7];
    const float* b0    = (const float*)d_in[8];
    const float* W_dn  = (const float*)d_in[9];
    const float* W_e1  = (const float*)d_in[10];
    const float* g1    = (const float*)d_in[11];
    const float* b1    = (const float*)d_in[12];
    const float* W_up  = (const float*)d_in[13];
    const float* W_dec = (const float*)d_in[14];
    const float* g_o   = (const float*)d_in[15];
    const float* b_o   = (const float*)d_in[16];
    const float* W_lin = (const float*)d_in[17];
    const float* b_lin = (const float*)d_in[18];

    const int N = in_sizes[0] / 3;
    const int M = in_sizes[2] / 27;

    // --- workspace: xvb bf16 [0..N*16 fl) (steps 3-4) / down fp32 [0..M*64 fl)
    // (steps 5-8) / up bf16 [0..N*16 fl) + decraw bf16 [N*16..N*32 fl)
    // (steps 10-13); stats at R ---
    float* wsf = (float*)d_ws;
    size_t R = (size_t)M * 64;
    if ((size_t)N * 32 > R) R = (size_t)N * 32;
    __hip_bfloat16* xvb = (__hip_bfloat16*)wsf;
    float* down = wsf;
    __hip_bfloat16* up     = (__hip_bfloat16*)wsf;
    __hip_bfloat16* decraw = (__hip_bfloat16*)(wsf + (size_t)N * 16);
    float* stats = wsf + R;
    // stats map: 0 sum0[32] | 32 sq0[32] | 64 sum1[64] | 128 sq1[64] |
    //            192 sumo[32] | 224 sqo[32] | 256 scale0 | 288 shift0 |
    //            320 scale1[64] | 384 shift1[64] | 448 scaleo | 480 shifto

    // --- d_out scratch: e0 bf16 [0..N*16 fl), e1raw bf16 [N*16..N*16+M*32 fl),
    // packed weights after; all dead before k_out writes y/feat ---
    __hip_bfloat16* e0    = (__hip_bfloat16*)d_out;
    __hip_bfloat16* e1raw = (__hip_bfloat16*)((float*)d_out + (size_t)N * 16);
    __hip_bfloat16* Wp0   = (__hip_bfloat16*)((float*)d_out + (size_t)N * 16 + (size_t)M * 32);
    const int T0 = 27 * 1 * 2 * 512;  // e0 pack: KT1 NT2
    const int T1 = 27 * 2 * 4 * 512;  // e1 pack: KT2 NT4
    const int T2 = 27 * 2 * 2 * 512;  // dec pack: KT2 NT2
    __hip_bfloat16* Wp1 = Wp0 + T0;
    __hip_bfloat16* Wp2 = Wp1 + T1;
    float* y    = (float*)d_out;
    float* feat = y + (size_t)N * 20;

    const int nblk = (N + 255) / 256;
    const int G = 2048;  // multiple of 8 (per-XCD slab / swizzle)

    hipMemsetAsync(stats, 0, 256 * sizeof(float), stream);
    k_pack<<<(T0 + 255) / 256, 256, 0, stream>>>(W_e0, Wp0, 32, 32, 1, 2, T0);
    k_pack<<<(T1 + 255) / 256, 256, 0, stream>>>(W_e1, Wp1, 64, 64, 2, 4, T1);
    k_pack<<<(T2 + 255) / 256, 256, 0, stream>>>(W_dec, Wp2, 64, 32, 2, 2, T2);

    k_xv<<<nblk, 256, 0, stream>>>(feats, nbr_f, W_sub, xvb, N);
    // fine convs: interleave + compaction + rotated 3-slot pipeline
    k_conv<32, 32, 0, 1, 1><<<G, 256, 0, stream>>>(xvb, nullptr, nbr_f, Wp0, e0, N,
                                                   stats + 0, stats + 32);
    // xvb dead; zero `down` (same region) for the atomic segment-sum
    hipMemsetAsync(down, 0, (size_t)M * 64 * sizeof(float), stream);
    k_fin<<<1, 64, 0, stream>>>(stats + 0, stats + 32, g0, b0,
                                stats + 256, stats + 288, 32, 1.f / (float)N);
    k_down<<<G, 256, 0, stream>>>(e0, parent, child, W_dn,
                                  stats + 256, stats + 288, down, N);
    // e1: MODE 1 fp32, contiguous-chunk map, NO compaction (proven 368us)
    k_conv<64, 64, 1, 0, 0><<<G, 256, 0, stream>>>(down, nullptr, nbr_c, Wp1, e1raw, M,
                                                   stats + 64, stats + 128);
    k_fin<<<1, 64, 0, stream>>>(stats + 64, stats + 128, g1, b1,
                                stats + 320, stats + 384, 64, 1.f / (float)M);
    k_up<<<G, 256, 0, stream>>>(e1raw, parent, child, W_up,
                                stats + 320, stats + 384, up, N);
    k_conv<64, 32, 2, 1, 1><<<G, 256, 0, stream>>>(e0, up, nbr_f, Wp2, decraw, N,
                                                   stats + 192, stats + 224);
    k_fin<<<1, 64, 0, stream>>>(stats + 192, stats + 224, g_o, b_o,
                                stats + 448, stats + 480, 32, 1.f / (float)N);
    k_out<<<nblk, 256, 0, stream>>>(decraw, stats + 448, stats + 480, W_lin, b_lin,
                                    y, feat, N);
}

// Round 11
// 1398.308 us; speedup vs baseline: 1.0829x; 1.0714x over previous
//
#include <hip/hip_runtime.h>
#include <hip/hip_bf16.h>

#define BN_EPS 1e-4f

typedef __attribute__((ext_vector_type(8))) short short8;   // 8 bf16 = 4 VGPR (MFMA A/B frag)
typedef __attribute__((ext_vector_type(4))) float float4e;  // MFMA C/D frag

__device__ __forceinline__ int rfl(int x) { return __builtin_amdgcn_readfirstlane(x); }

__device__ __forceinline__ float ldf(const __hip_bfloat16* p) { return __bfloat162float(*p); }
__device__ __forceinline__ void stf(__hip_bfloat16* p, float v) { *p = __float2bfloat16(v); }

__device__ __forceinline__ short bfbits(float x) {
    __hip_bfloat16 h = __float2bfloat16(x);
    short s;
    __builtin_memcpy(&s, &h, 2);
    return s;
}
__device__ __forceinline__ short8 cvt8(float4 a, float4 b) {
    short8 r;
    r[0] = bfbits(a.x); r[1] = bfbits(a.y); r[2] = bfbits(a.z); r[3] = bfbits(a.w);
    r[4] = bfbits(b.x); r[5] = bfbits(b.y); r[6] = bfbits(b.z); r[7] = bfbits(b.w);
    return r;
}

// ---- pack W fp32 [27][CIN][COUT] -> bf16 B-fragment table [27][KT][NT][lane][8] ----
// element j of lane = W[t][kt*32 + (lane>>4)*8 + j][nt*16 + (lane&15)]
__global__ __launch_bounds__(256) void k_pack(const float* __restrict__ src,
                                              __hip_bfloat16* __restrict__ dst,
                                              int CIN, int COUT, int KT, int NT, int total) {
    int i = blockIdx.x * 256 + threadIdx.x;
    if (i >= total) return;
    int j = i & 7, lane = (i >> 3) & 63;
    int g = i >> 9;
    int nt = g % NT; g /= NT;
    int kt = g % KT; g /= KT;
    int t = g;
    int q = lane >> 4, c = lane & 15;
    dst[i] = __float2bfloat16(src[((size_t)t * CIN + kt * 32 + q * 8 + j) * COUT + nt * 16 + c]);
}

// ---------------- xv = subconv(feats[N,3], nbr_fine, W_sub) -> bf16 ----------------
// Round-11 rewrite: BRANCHLESS GROUPED-MLP gathers. The old per-tap
// `if (idx<0) continue` made every gather control-dependent -> 27 serial
// exposed latencies per thread. Now: all 27 idx loaded up front; 3 groups of
// 9 taps; each group issues 27 clamped unconditional loads (deep MLP), then
// predicated FMA (m = idx>=0 ? 1 : 0; +0.0 terms exact). Arrays fully
// unrolled, constant indices -> registers (runtime-indexed arrays spill).
__global__ __launch_bounds__(256) void k_xv(const float* __restrict__ feats,
                                            const int* __restrict__ nbr,
                                            const float* __restrict__ W,
                                            __hip_bfloat16* __restrict__ out, int N) {
    int n = blockIdx.x * 256 + threadIdx.x;
    if (n >= N) return;
    float acc[32];
#pragma unroll
    for (int d = 0; d < 32; ++d) acc[d] = 0.f;
    const int* nb = nbr + (size_t)n * 27;
    int idx[27];
#pragma unroll
    for (int k = 0; k < 27; ++k) idx[k] = nb[k];
#pragma unroll
    for (int g = 0; g < 3; ++g) {
        float fx[9], fy[9], fz[9];
#pragma unroll
        for (int j = 0; j < 9; ++j) {
            int id = idx[g * 9 + j];
            size_t c = (size_t)(id < 0 ? 0 : id);
            const float* p = feats + c * 3;
            fx[j] = p[0]; fy[j] = p[1]; fz[j] = p[2];
        }
#pragma unroll
        for (int j = 0; j < 9; ++j) {
            int k = g * 9 + j;
            float m = idx[k] >= 0 ? 1.f : 0.f;
            float f0 = fx[j] * m, f1 = fy[j] * m, f2 = fz[j] * m;
            const float* w = W + k * 96;  // k constant -> scalar loads
#pragma unroll
            for (int d = 0; d < 32; ++d)
                acc[d] += f0 * w[d] + f1 * w[32 + d] + f2 * w[64 + d];
        }
    }
    short8* o = (short8*)(out + (size_t)n * 32);
#pragma unroll
    for (int c = 0; c < 4; ++c) {
        short8 r;
#pragma unroll
        for (int j = 0; j < 8; ++j) r[j] = bfbits(acc[c * 8 + j]);
        o[c] = r;
    }
}

// ---------------- MFMA submanifold conv ----------------
// Wave per 16-row tile. Template knobs (A/B-isolated across rounds 4-10):
//  MAP 0: per-XCD slab, CONTIGUOUS chunk per wave (best for COARSE conv:
//         e1 MODE1 = 368-381 us; interleave regressed it to 466 us).
//  MAP 1: per-XCD slab, within-slab wave INTERLEAVE (best for FINE convs:
//         instant window ~2 MB fits L2).
//  COMPACT 1: active-tap compaction (wave-OR 27-bit mask, order-preserving
//         list via ballot-prefix; walk only nact taps — fine grid ~9/27).
//         Rotated 3-slot modulo pipeline (no register shifts). NOTE
//         (rounds 9-10): pipeline depth beyond 2 is NULL for fine convs —
//         both 5-slot shift and 3-slot rotation landed within noise of the
//         2-deep baseline; at ~12 waves/CU, TLP already hides gather
//         latency. Depth is exhausted as a lever; do not retry.
//  COMPACT 0: plain 27-tap loop, 3 shifting slots, per-tap ballots — e1 only
//         (~all taps active; e1 is cache-BW-bound at ~6.6 TB/s effective).
//         Kept byte-identical to the 1490us-proven round-8 build.
// Per tap: out[16,COUT] += A(rows)[16,CIN] @ W[tap]. A-frag gathered directly
// from global (lane reads 16B at in + idx*CIN + kt*32 + (lane>>4)*8). Row idx
// from ROW-MAJOR LDS table (stride-27 -> conflict-free, measured 0). All
// pipeline state NAMED scalars (arrays spill to scratch).
// ERRATUM (rounds 1-3, 6): ANY bf16-A instantiation at the e1 shape
// (KT=2, NT=4) — MODE 0 single-src (3 idioms) AND MODE 2 dual-src — runs
// 2.8x slower with ~1.2 GB fetch + ~0.84 GB write per dispatch (scratch
// round-trip signature). dec (KT=2,NT=2,MODE 2) and e0 (KT=1) are clean.
// Pathology is instantiation-shape-bound. e1 is LOCKED to MODE 1 fp32.
// MODE 0: bf16 single src (CIN=32) | 1: fp32 src + in-reg cvt (CIN=64)
// | 2: bf16 dual src A|B halves (CIN=64).
template <int CIN, int COUT, int MODE, int MAP, int COMPACT>
__global__ __launch_bounds__(256, 4) void k_conv(const void* __restrict__ inAv,
                                                 const void* __restrict__ inBv,
                                                 const int* __restrict__ nbr,
                                                 const __hip_bfloat16* __restrict__ Wp,
                                                 __hip_bfloat16* __restrict__ out,
                                                 int nrows,
                                                 float* __restrict__ ssum,
                                                 float* __restrict__ ssq) {
    constexpr int KT = CIN / 32;   // MFMA k-tiles
    constexpr int NT = COUT / 16;  // MFMA n-tiles
    static_assert(KT == 1 || KT == 2, "KT must be 1 or 2");
    static_assert(!(COMPACT == 1 && MODE == 1), "compact path is bf16-only");
    __shared__ int sidx[4][432];   // per-wave idx table, row-major [row][tap]
    __shared__ int slist[4][32];   // per-wave compact active-tap list (COMPACT)
    const __hip_bfloat16* inAb = (const __hip_bfloat16*)inAv;
    const __hip_bfloat16* inBb = (const __hip_bfloat16*)inBv;
    const float* inAf = (const float*)inAv;
    const int tid = threadIdx.x;
    const int lane = tid & 63;
    const int wv = tid >> 6;
    const int m15 = lane & 15;
    const int q = lane >> 4;
    int* my = sidx[wv];
    int* lst = slist[wv];
    const int ntile = (nrows + 15) / 16;
    const int b = blockIdx.x;
    // ---- tile range per wave (MAP) ----
    int start, tend, tstep;
    if constexpr (MAP == 0) {
        // bijective XCD swizzle + contiguous chunk per wave
        const int bs = (b & 7) * (gridDim.x >> 3) + (b >> 3);
        const int w = bs * 4 + wv;
        const int nw = gridDim.x * 4;
        const int cq = ntile / nw, cr = ntile % nw;
        start = w * cq + (w < cr ? w : cr);
        tend = start + cq + (w < cr ? 1 : 0);
        tstep = 1;
    } else {
        // per-XCD slab + within-slab wave interleave
        const int xcd = b & 7;
        const int wpx = (gridDim.x >> 3) * 4;
        const int lw = (b >> 3) * 4 + wv;
        const int s0 = (int)(((long long)xcd * ntile) >> 3);
        const int s1 = (int)(((long long)(xcd + 1) * ntile) >> 3);
        start = s0 + lw;
        tend = s1;
        tstep = wpx;
    }
    float sS[NT], sQ[NT];
#pragma unroll
    for (int nt = 0; nt < NT; ++nt) { sS[nt] = 0.f; sQ[nt] = 0.f; }

    const short8 z8 = (short8)(short)0;

    for (int tile = start; tile < tend; tile += tstep) {
        const int row0 = rfl(tile) * 16;
        int nr = nrows - row0;
        nr = nr > 16 ? 16 : nr;
        const int* src = nbr + (size_t)row0 * 27;
        const int tot = nr * 27;
        float4e acc[NT];
#pragma unroll
        for (int nt = 0; nt < NT; ++nt) acc[nt] = (float4e)0.f;

        if constexpr (COMPACT) {
            // ---- stage idx row-major + tap-activity mask + compact list ----
            unsigned ab = 0;
            for (int t = lane; t < 432; t += 64) {
                int v = (t < tot) ? src[t] : -1;
                my[t] = v;
                if (v >= 0) ab |= (1u << (t % 27));
            }
#pragma unroll
            for (int s = 1; s < 64; s <<= 1) ab |= __shfl_xor((int)ab, s);
            {
                bool act = (lane < 27) && ((ab >> lane) & 1u);
                unsigned long long bal = __ballot(act);
                if (act) lst[__popcll(bal & ((1ull << lane) - 1ull))] = lane;
            }
            const int nact = __popc((int)ab);  // wave-uniform

            auto load_s = [&](int ir, short8& s0_, short8& s1_) {
                size_t id = (size_t)(ir < 0 ? 0 : ir);
                if constexpr (MODE == 0) {
                    s0_ = *(const short8*)(inAb + id * CIN + q * 8);
                    if constexpr (KT == 2)
                        s1_ = *(const short8*)(inAb + id * CIN + 32 + q * 8);
                } else {  // MODE 2
                    s0_ = *(const short8*)(inAb + id * 32 + q * 8);
                    s1_ = *(const short8*)(inBb + id * 32 + q * 8);
                }
            };
            auto mfma_s = [&](int ktap, int irv, short8 a0, short8 a1) {
                a0 = (irv >= 0) ? a0 : z8;
                if constexpr (KT == 2) a1 = (irv >= 0) ? a1 : z8;
                const short8* bp = (const short8*)Wp + (size_t)ktap * (KT * NT * 64) + lane;
#pragma unroll
                for (int nt = 0; nt < NT; ++nt) {
                    acc[nt] = __builtin_amdgcn_mfma_f32_16x16x32_bf16(a0, bp[nt * 64], acc[nt], 0, 0, 0);
                    if constexpr (KT == 2)
                        acc[nt] = __builtin_amdgcn_mfma_f32_16x16x32_bf16(a1, bp[(NT + nt) * 64], acc[nt], 0, 0, 0);
                }
            };

            // ---- rotated 3-slot modulo pipeline (no register shifts) ----
            short8 sX0 = z8, sX1 = z8, sY0 = z8, sY1 = z8, sZ0 = z8, sZ1 = z8;
            int kX = 0, kY = 0, kZ = 0, irX = -1, irY = -1, irZ = -1;
            if (0 < nact) { kX = lst[0]; irX = my[m15 * 27 + kX]; load_s(irX, sX0, sX1); }
            if (1 < nact) { kY = lst[1]; irY = my[m15 * 27 + kY]; load_s(irY, sY0, sY1); }
            if (2 < nact) { kZ = lst[2]; irZ = my[m15 * 27 + kZ]; load_s(irZ, sZ0, sZ1); }
            int i = 0;
            while (i < nact) {
                mfma_s(kX, irX, sX0, sX1);
                if (i + 3 < nact) { kX = lst[i + 3]; irX = my[m15 * 27 + kX]; load_s(irX, sX0, sX1); }
                if (++i >= nact) break;
                mfma_s(kY, irY, sY0, sY1);
                if (i + 3 < nact) { kY = lst[i + 3]; irY = my[m15 * 27 + kY]; load_s(irY, sY0, sY1); }
                if (++i >= nact) break;
                mfma_s(kZ, irZ, sZ0, sZ1);
                if (i + 3 < nact) { kZ = lst[i + 3]; irZ = my[m15 * 27 + kZ]; load_s(irZ, sZ0, sZ1); }
                ++i;
            }
        } else {
            // ---- plain 27-tap loop, 3 shifting slots, per-tap ballots ----
            // (byte-identical to the 1490us round-8 build; e1 only)
            for (int t = lane; t < 432; t += 64) my[t] = (t < tot) ? src[t] : -1;

            short8 sA0 = z8, sA1 = z8, sB0 = z8, sB1 = z8, sC0 = z8, sC1 = z8;
            float4 fA0{}, fA1{}, fA2{}, fA3{};
            float4 fB0{}, fB1{}, fB2{}, fB3{};
            float4 fC0{}, fC1{}, fC2{}, fC3{};

            auto load_g = [&](int ir, short8& s0_, short8& s1_,
                              float4& f0, float4& f1, float4& f2, float4& f3) {
                size_t id = (size_t)(ir < 0 ? 0 : ir);
                if constexpr (MODE == 0) {
                    s0_ = *(const short8*)(inAb + id * CIN + q * 8);
                    if constexpr (KT == 2)
                        s1_ = *(const short8*)(inAb + id * CIN + 32 + q * 8);
                } else if constexpr (MODE == 2) {
                    s0_ = *(const short8*)(inAb + id * 32 + q * 8);
                    s1_ = *(const short8*)(inBb + id * 32 + q * 8);
                } else {
                    const float* bb = inAf + id * 64 + q * 8;
                    f0 = *(const float4*)(bb);
                    f1 = *(const float4*)(bb + 4);
                    f2 = *(const float4*)(bb + 32);
                    f3 = *(const float4*)(bb + 36);
                }
            };

            int irA = my[m15 * 27 + 0];
            int irB = my[m15 * 27 + 1];
            int irC = my[m15 * 27 + 2];
            int mA = rfl((int)(__ballot(irA >= 0) & 0xffff));
            int mB = rfl((int)(__ballot(irB >= 0) & 0xffff));
            if (mA) load_g(irA, sA0, sA1, fA0, fA1, fA2, fA3);
            if (mB) load_g(irB, sB0, sB1, fB0, fB1, fB2, fB3);
            for (int k = 0; k < 27; ++k) {
                int mC = rfl((int)(__ballot(irC >= 0) & 0xffff));
                int irD = -1;
                if (k + 3 < 27) irD = my[m15 * 27 + (k + 3)];
                if (mC) load_g(irC, sC0, sC1, fC0, fC1, fC2, fC3);
                if (mA) {
                    short8 a0, a1;
                    if constexpr (MODE == 1) {
                        a0 = cvt8(fA0, fA1);
                        a1 = cvt8(fA2, fA3);
                    } else {
                        a0 = sA0;
                        a1 = sA1;
                    }
                    a0 = (irA >= 0) ? a0 : z8;
                    if constexpr (KT == 2) a1 = (irA >= 0) ? a1 : z8;
                    const short8* bp = (const short8*)Wp + (size_t)k * KT * NT * 64 + lane;
#pragma unroll
                    for (int nt = 0; nt < NT; ++nt) {
                        acc[nt] = __builtin_amdgcn_mfma_f32_16x16x32_bf16(a0, bp[nt * 64], acc[nt], 0, 0, 0);
                        if constexpr (KT == 2)
                            acc[nt] = __builtin_amdgcn_mfma_f32_16x16x32_bf16(a1, bp[(NT + nt) * 64], acc[nt], 0, 0, 0);
                    }
                }
                mA = mB; mB = mC;
                irA = irB; irB = irC; irC = irD;
                if constexpr (MODE == 1) {
                    fA0 = fB0; fA1 = fB1; fA2 = fB2; fA3 = fB3;
                    fB0 = fC0; fB1 = fC1; fB2 = fC2; fB3 = fC3;
                } else {
                    sA0 = sB0; sB0 = sC0;
                    if constexpr (KT == 2) { sA1 = sB1; sB1 = sC1; }
                }
            }
        }
        // ---- store C (col=lane&15, row=quad*4+reg) + BN stats ----
#pragma unroll
        for (int nt = 0; nt < NT; ++nt) {
#pragma unroll
            for (int r = 0; r < 4; ++r) {
                int rowg = row0 + q * 4 + r;
                if (rowg < nrows) {
                    float v = acc[nt][r];
                    stf(out + (size_t)rowg * COUT + nt * 16 + m15, v);
                    sS[nt] += v;
                    sQ[nt] += v * v;
                }
            }
        }
    }
    // ---- stats: reduce over quads (same col), one atomic per (col,nt) ----
#pragma unroll
    for (int nt = 0; nt < NT; ++nt) {
        float v = sS[nt], w2 = sQ[nt];
        v += __shfl_xor(v, 16); v += __shfl_xor(v, 32);
        w2 += __shfl_xor(w2, 16); w2 += __shfl_xor(w2, 32);
        if (lane < 16) {
            atomicAdd(&ssum[nt * 16 + lane], v);
            atomicAdd(&ssq[nt * 16 + lane], w2);
        }
    }
}

// ---------------- BN finalize: scale/shift from sums ----------------
__global__ void k_fin(const float* __restrict__ ssum, const float* __restrict__ ssq,
                      const float* __restrict__ g, const float* __restrict__ b,
                      float* __restrict__ scale, float* __restrict__ shift,
                      int C, float invN) {
    int c = blockIdx.x * blockDim.x + threadIdx.x;
    if (c >= C) return;
    float mu = ssum[c] * invN;
    float var = fmaxf(ssq[c] * invN - mu * mu, 0.f);
    float s = g[c] * rsqrtf(var + BN_EPS);
    scale[c] = s;
    shift[c] = b[c] - mu * s;
}

// ---- e0 = bnrelu(e0raw) in place (bf16); down[parent] += e0 @ W_down[off] (fp32 atomics) ----
__global__ __launch_bounds__(256) void k_down(__hip_bfloat16* __restrict__ e0,
                                              const int* __restrict__ parent,
                                              const int* __restrict__ child,
                                              const float* __restrict__ Wd,
                                              const float* __restrict__ sc,
                                              const float* __restrict__ sh,
                                              float* __restrict__ down, int N) {
    const int lane = threadIdx.x & 63;
    int wid = blockIdx.x * 4 + (threadIdx.x >> 6);
    int nw = gridDim.x * 4;
    for (int row = wid; row < N; row += nw) {
        int urow = rfl(row);
        float v = 0.f;
        if (lane < 32) {
            float r = ldf(e0 + (size_t)urow * 32 + lane);
            v = fmaxf(fmaf(r, sc[lane], sh[lane]), 0.f);
            stf(e0 + (size_t)urow * 32 + lane, v);  // post-BN e0, consumed by dec
        }
        int par = rfl(parent[urow]);
        int off = rfl(child[urow]);
        float acc = 0.f;
        const float* wb = Wd + (size_t)off * 2048 + lane;  // W_down[off][c][lane]
#pragma unroll
        for (int c = 0; c < 32; ++c)
            acc = fmaf(__shfl(v, c), wb[c * 64], acc);
        atomicAdd(&down[(size_t)par * 64 + lane], acc);
    }
}

// ---- up[n] = bnrelu(e1raw)[parent[n]] @ W_up[off[n]] -> bf16 ----
__global__ __launch_bounds__(256) void k_up(const __hip_bfloat16* __restrict__ e1raw,
                                            const int* __restrict__ parent,
                                            const int* __restrict__ child,
                                            const float* __restrict__ Wu,
                                            const float* __restrict__ sc,
                                            const float* __restrict__ sh,
                                            __hip_bfloat16* __restrict__ up, int N) {
    const int lane = threadIdx.x & 63;
    int wid = blockIdx.x * 4 + (threadIdx.x >> 6);
    int nw = gridDim.x * 4;
    for (int row = wid; row < N; row += nw) {
        int urow = rfl(row);
        int par = rfl(parent[urow]);
        int off = rfl(child[urow]);
        float e = ldf(e1raw + (size_t)par * 64 + lane);
        float v = fmaxf(fmaf(e, sc[lane], sh[lane]), 0.f);  // BN on the fly
        int d = lane & 31, hi = lane >> 5;
        float acc = 0.f;
        const float* wb = Wu + (size_t)off * 2048 + (size_t)hi * 1024 + d;
#pragma unroll
        for (int c = 0; c < 32; ++c)
            acc = fmaf(__shfl(v, hi * 32 + c), wb[c * 32], acc);
        acc += __shfl_xor(acc, 32);
        if (hi == 0) stf(up + (size_t)urow * 32 + d, acc);
    }
}

// ---- feature = bnrelu(decraw); y = feature @ W_lin + b_lin ----
__global__ __launch_bounds__(256) void k_out(const __hip_bfloat16* __restrict__ dec,
                                             const float* __restrict__ sc,
                                             const float* __restrict__ sh,
                                             const float* __restrict__ Wl,
                                             const float* __restrict__ bl,
                                             float* __restrict__ y,
                                             float* __restrict__ feat, int N) {
    int n = blockIdx.x * 256 + threadIdx.x;
    if (n >= N) return;
    float f[32];
    const __hip_bfloat162* p = (const __hip_bfloat162*)(dec + (size_t)n * 32);
#pragma unroll
    for (int j = 0; j < 16; ++j) {
        float2 t = __bfloat1622float2(p[j]);
        f[2 * j + 0] = fmaxf(fmaf(t.x, sc[2 * j + 0], sh[2 * j + 0]), 0.f);
        f[2 * j + 1] = fmaxf(fmaf(t.y, sc[2 * j + 1], sh[2 * j + 1]), 0.f);
    }
    float4* fo = (float4*)(feat + (size_t)n * 32);
#pragma unroll
    for (int j = 0; j < 8; ++j)
        fo[j] = make_float4(f[4 * j], f[4 * j + 1], f[4 * j + 2], f[4 * j + 3]);
    float acc[20];
#pragma unroll
    for (int qq = 0; qq < 20; ++qq) acc[qq] = bl[qq];
#pragma unroll
    for (int c = 0; c < 32; ++c) {
        float fc = f[c];
#pragma unroll
        for (int qq = 0; qq < 20; ++qq) acc[qq] = fmaf(fc, Wl[c * 20 + qq], acc[qq]);
    }
    float4* yo = (float4*)(y + (size_t)n * 20);
#pragma unroll
    for (int j = 0; j < 5; ++j)
        yo[j] = make_float4(acc[4 * j], acc[4 * j + 1], acc[4 * j + 2], acc[4 * j + 3]);
}

extern "C" void kernel_launch(void* const* d_in, const int* in_sizes, int n_in,
                              void* d_out, int out_size, void* d_ws, size_t ws_size,
                              hipStream_t stream) {
    const float* feats = (const float*)d_in[0];
    const int* nbr_f   = (const int*)d_in[1];
    const int* nbr_c   = (const int*)d_in[2];
    const int* parent  = (const int*)d_in[3];
    const int* child   = (const int*)d_in[4];
    const float* W_sub = (const float*)d_in[5];
    const float* W_e0  = (const float*)d_in[6];
    const float* g0    = (const float*)d_in[7];
    const float* b0    = (const float*)d_in[8];
    const float* W_dn  = (const float*)d_in[9];
    const float* W_e1  = (const float*)d_in[10];
    const float* g1    = (const float*)d_in[11];
    const float* b1    = (const float*)d_in[12];
    const float* W_up  = (const float*)d_in[13];
    const float* W_dec = (const float*)d_in[14];
    const float* g_o   = (const float*)d_in[15];
    const float* b_o   = (const float*)d_in[16];
    const float* W_lin = (const float*)d_in[17];
    const float* b_lin = (const float*)d_in[18];

    const int N = in_sizes[0] / 3;
    const int M = in_sizes[2] / 27;

    // --- workspace: xvb bf16 [0..N*16 fl) (steps 3-4) / down fp32 [0..M*64 fl)
    // (steps 5-8) / up bf16 [0..N*16 fl) + decraw bf16 [N*16..N*32 fl)
    // (steps 10-13); stats at R ---
    float* wsf = (float*)d_ws;
    size_t R = (size_t)M * 64;
    if ((size_t)N * 32 > R) R = (size_t)N * 32;
    __hip_bfloat16* xvb = (__hip_bfloat16*)wsf;
    float* down = wsf;
    __hip_bfloat16* up     = (__hip_bfloat16*)wsf;
    __hip_bfloat16* decraw = (__hip_bfloat16*)(wsf + (size_t)N * 16);
    float* stats = wsf + R;
    // stats map: 0 sum0[32] | 32 sq0[32] | 64 sum1[64] | 128 sq1[64] |
    //            192 sumo[32] | 224 sqo[32] | 256 scale0 | 288 shift0 |
    //            320 scale1[64] | 384 shift1[64] | 448 scaleo | 480 shifto

    // --- d_out scratch: e0 bf16 [0..N*16 fl), e1raw bf16 [N*16..N*16+M*32 fl),
    // packed weights after; all dead before k_out writes y/feat ---
    __hip_bfloat16* e0    = (__hip_bfloat16*)d_out;
    __hip_bfloat16* e1raw = (__hip_bfloat16*)((float*)d_out + (size_t)N * 16);
    __hip_bfloat16* Wp0   = (__hip_bfloat16*)((float*)d_out + (size_t)N * 16 + (size_t)M * 32);
    const int T0 = 27 * 1 * 2 * 512;  // e0 pack: KT1 NT2
    const int T1 = 27 * 2 * 4 * 512;  // e1 pack: KT2 NT4
    const int T2 = 27 * 2 * 2 * 512;  // dec pack: KT2 NT2
    __hip_bfloat16* Wp1 = Wp0 + T0;
    __hip_bfloat16* Wp2 = Wp1 + T1;
    float* y    = (float*)d_out;
    float* feat = y + (size_t)N * 20;

    const int nblk = (N + 255) / 256;
    const int G = 2048;  // multiple of 8 (per-XCD slab / swizzle)

    hipMemsetAsync(stats, 0, 256 * sizeof(float), stream);
    k_pack<<<(T0 + 255) / 256, 256, 0, stream>>>(W_e0, Wp0, 32, 32, 1, 2, T0);
    k_pack<<<(T1 + 255) / 256, 256, 0, stream>>>(W_e1, Wp1, 64, 64, 2, 4, T1);
    k_pack<<<(T2 + 255) / 256, 256, 0, stream>>>(W_dec, Wp2, 64, 32, 2, 2, T2);

    k_xv<<<nblk, 256, 0, stream>>>(feats, nbr_f, W_sub, xvb, N);
    // fine convs: interleave + compaction + rotated 3-slot pipeline
    k_conv<32, 32, 0, 1, 1><<<G, 256, 0, stream>>>(xvb, nullptr, nbr_f, Wp0, e0, N,
                                                   stats + 0, stats + 32);
    // xvb dead; zero `down` (same region) for the atomic segment-sum
    hipMemsetAsync(down, 0, (size_t)M * 64 * sizeof(float), stream);
    k_fin<<<1, 64, 0, stream>>>(stats + 0, stats + 32, g0, b0,
                                stats + 256, stats + 288, 32, 1.f / (float)N);
    k_down<<<G, 256, 0, stream>>>(e0, parent, child, W_dn,
                                  stats + 256, stats + 288, down, N);
    // e1: MODE 1 fp32, contiguous-chunk map, NO compaction (proven 368us)
    k_conv<64, 64, 1, 0, 0><<<G, 256, 0, stream>>>(down, nullptr, nbr_c, Wp1, e1raw, M,
                                                   stats + 64, stats + 128);
    k_fin<<<1, 64, 0, stream>>>(stats + 64, stats + 128, g1, b1,
                                stats + 320, stats + 384, 64, 1.f / (float)M);
    k_up<<<G, 256, 0, stream>>>(e1raw, parent, child, W_up,
                                stats + 320, stats + 384, up, N);
    k_conv<64, 32, 2, 1, 1><<<G, 256, 0, stream>>>(e0, up, nbr_f, Wp2, decraw, N,
                                                   stats + 192, stats + 224);
    k_fin<<<1, 64, 0, stream>>>(stats + 192, stats + 224, g_o, b_o,
                                stats + 448, stats + 480, 32, 1.f / (float)N);
    k_out<<<nblk, 256, 0, stream>>>(decraw, stats + 448, stats + 480, W_lin, b_lin,
                                    y, feat, N);
}